// Round 1
// 539.090 us; speedup vs baseline: 1.1361x; 1.1361x over previous
//
#include <hip/hip_runtime.h>
#include <stdint.h>

// Problem constants
#define N_B 8
#define F_T 16
#define S_T 196
#define D_M 1024
#define H_N 8
#define HD  128
#define L_T 3137              // 1 + F*S
#define M_R (N_B * L_T)       // 25096 real rows
#define M_P 25216             // 197*128 padded rows (buffers sized to this)

typedef __attribute__((ext_vector_type(8))) short bf16x8;
typedef __attribute__((ext_vector_type(4))) float f32x4;

__device__ __forceinline__ float b2f(unsigned int u) {
  union { unsigned int i; float f; } x; x.i = u << 16; return x.f;
}
__device__ __forceinline__ unsigned short f2b(float f) {
  union { float f; unsigned int i; } x; x.f = f;
  unsigned int r = x.i + 0x7fffu + ((x.i >> 16) & 1u);  // RNE
  return (unsigned short)(r >> 16);
}

// ---------------- convert fp32 x -> bf16, zero-pad rows M_R..M_P ----------------
__global__ __launch_bounds__(256) void convert_pad(const float* __restrict__ x,
                                                   unsigned short* __restrict__ xb,
                                                   int nreal) {
  int i = (blockIdx.x * 256 + threadIdx.x) * 4;
  float4 v;
  if (i < nreal) v = *(const float4*)(x + i);
  else { v.x = 0.f; v.y = 0.f; v.z = 0.f; v.w = 0.f; }
  ushort4 o;
  o.x = f2b(v.x); o.y = f2b(v.y); o.z = f2b(v.z); o.w = f2b(v.w);
  *(ushort4*)(xb + i) = o;
}

// ---------------- transpose 5 weights: W[k][n] fp32 -> Wt[n][k] bf16 ----------------
struct WP { const float* s[5]; unsigned short* d[5]; };
__global__ __launch_bounds__(256) void transpose5(WP p) {
  __shared__ float t[32][33];
  const int w = blockIdx.z;
  const float* W = p.s[w];
  unsigned short* Wt = p.d[w];
  const int tx = threadIdx.x, ty = threadIdx.y;    // 32 x 8
  const int n0 = blockIdx.x * 32, k0 = blockIdx.y * 32;
#pragma unroll
  for (int i = 0; i < 4; i++)
    t[ty + i * 8][tx] = W[(size_t)(k0 + ty + i * 8) * D_M + n0 + tx];
  __syncthreads();
#pragma unroll
  for (int i = 0; i < 4; i++)
    Wt[(size_t)(n0 + ty + i * 8) * D_M + k0 + tx] = f2b(t[tx][ty + i * 8]);
}

// ---------------- 256x256 GEMM, BK=64, 8 waves, counted-vmcnt deep pipeline ----------------
__device__ __forceinline__ void async16(const unsigned short* g, unsigned short* l) {
  __builtin_amdgcn_global_load_lds((const __attribute__((address_space(1))) void*)g,
                                   (__attribute__((address_space(3))) void*)l, 16, 0, 0);
}

struct Outs { void* p[3]; };

// 16 MFMAs: one m-half x all n, one k-half.
#define MFMA_Q(AV, MLO)                                                        \
  __builtin_amdgcn_s_setprio(1);                                               \
  _Pragma("unroll") for (int m_ = 0; m_ < 4; ++m_)                             \
      _Pragma("unroll") for (int n_ = 0; n_ < 4; ++n_)                         \
          acc[(MLO) + m_][n_] = __builtin_amdgcn_mfma_f32_16x16x32_bf16(       \
              AV[(MLO) + m_], bv[n_], acc[(MLO) + m_][n_], 0, 0, 0);           \
  __builtin_amdgcn_s_setprio(0);

// One K-tile: 4 phases.
//  P0: stage B(t+1) h0 | read av0[0..3],bv(ks0),av1[0..3] | MFMA ks0 m0-3
//  P1: stage B(t+1) h1 | read av0[4..7],av1[4..7]         | MFMA ks0 m4-7
//      lgkmcnt(0) + barrier   (A region of BUF now dead -> safe to DMA into)
//  P2: stage A(t+2) h0 | read bv(ks1)                     | MFMA ks1 m0-3
//  P3: stage A(t+2) h1 |                                  | MFMA ks1 m4-7
//      vmcnt(VMN) + lgkmcnt(0) + barrier (VMN=4 steady: A(t+2) may stay in flight)
#define TILE_ONE(T, BUF, STGB, STGA, VMN)                                      \
  do {                                                                         \
    const unsigned short* Ab = sA + (BUF) * 16384 + aOff;                      \
    const unsigned short* Bb = sB + (BUF) * 16384 + bOff;                      \
    if (STGB) {                                                                \
      async16(gB + ((T) + 1) * 64,          sBst + (1 - (BUF)) * 16384);       \
      async16(gB + ((T) + 1) * 64 + 65536,  sBst + (1 - (BUF)) * 16384 + 4096);\
    }                                                                          \
    _Pragma("unroll") for (int m_ = 0; m_ < 4; ++m_)                           \
        av0[m_] = *(const bf16x8*)(Ab + m_ * 1024 + sl0);                      \
    _Pragma("unroll") for (int n_ = 0; n_ < 4; ++n_)                           \
        bv[n_] = *(const bf16x8*)(Bb + n_ * 1024 + sl0);                       \
    _Pragma("unroll") for (int m_ = 0; m_ < 4; ++m_)                           \
        av1[m_] = *(const bf16x8*)(Ab + m_ * 1024 + sl1);                      \
    MFMA_Q(av0, 0)                                                             \
    if (STGB) {                                                                \
      async16(gB + ((T) + 1) * 64 + 131072, sBst + (1 - (BUF)) * 16384 + 8192);\
      async16(gB + ((T) + 1) * 64 + 196608, sBst + (1 - (BUF)) * 16384 + 12288);\
    }                                                                          \
    _Pragma("unroll") for (int m_ = 0; m_ < 4; ++m_)                           \
        av0[4 + m_] = *(const bf16x8*)(Ab + (4 + m_) * 1024 + sl0);            \
    _Pragma("unroll") for (int m_ = 0; m_ < 4; ++m_)                           \
        av1[4 + m_] = *(const bf16x8*)(Ab + (4 + m_) * 1024 + sl1);            \
    MFMA_Q(av0, 4)                                                             \
    asm volatile("s_waitcnt lgkmcnt(0)" ::: "memory");                         \
    __builtin_amdgcn_s_barrier();                                              \
    asm volatile("" ::: "memory");                                             \
    if (STGA) {                                                                \
      async16(gA + ((T) + 2) * 64,          sAst + (BUF) * 16384);             \
      async16(gA + ((T) + 2) * 64 + 65536,  sAst + (BUF) * 16384 + 4096);      \
    }                                                                          \
    _Pragma("unroll") for (int n_ = 0; n_ < 4; ++n_)                           \
        bv[n_] = *(const bf16x8*)(Bb + n_ * 1024 + sl1);                       \
    MFMA_Q(av1, 0)                                                             \
    if (STGA) {                                                                \
      async16(gA + ((T) + 2) * 64 + 131072, sAst + (BUF) * 16384 + 8192);      \
      async16(gA + ((T) + 2) * 64 + 196608, sAst + (BUF) * 16384 + 12288);     \
    }                                                                          \
    MFMA_Q(av1, 4)                                                             \
    if ((VMN) == 4)                                                            \
      asm volatile("s_waitcnt vmcnt(4) lgkmcnt(0)" ::: "memory");              \
    else if ((VMN) == 0)                                                       \
      asm volatile("s_waitcnt vmcnt(0) lgkmcnt(0)" ::: "memory");              \
    else                                                                       \
      asm volatile("s_waitcnt lgkmcnt(0)" ::: "memory");                       \
    __builtin_amdgcn_s_barrier();                                              \
    asm volatile("" ::: "memory");                                             \
  } while (0)

// MODE 1: bf16 out + bias. MODE 2: fp32 out + bias, row guard. MODE 3: bf16, 3 outs (QKV).
template <int MODE>
__global__ __launch_bounds__(512, 2) void gemm_bt(const unsigned short* __restrict__ A,
                                                  const unsigned short* __restrict__ Bt,
                                                  const float* __restrict__ bias,
                                                  Outs o, int Mreal) {
  // LDS: A dbuf 2x[256][64] u16 (32KB ea) + B dbuf same = 128 KiB exactly.
  __shared__ __align__(16) unsigned short lds[65536];
  unsigned short* sA = lds;
  unsigned short* sB = lds + 32768;

  const int tid = threadIdx.x;
  const int lane = tid & 63;
  const int wv = tid >> 6;           // 0..7
  const int wm = wv >> 2, wn = wv & 3;
  const int l15 = lane & 15, kg = lane >> 4;

  // --- block -> (rowTile, colTile): bijective XCD chunks, 4-col bands (B set = 2MB/L2)
  constexpr int NCT = (MODE == 3) ? 12 : 4;
  constexpr int NWG = 99 * NCT;
  constexpr int Q8 = NWG >> 3, R8 = NWG & 7;
  const int xcd = blockIdx.x & 7, off = blockIdx.x >> 3;
  const int lin = (xcd < R8 ? xcd * (Q8 + 1) : R8 * (Q8 + 1) + (xcd - R8) * Q8) + off;
  const int band = lin / 396;                      // 396 = 99 rowTiles * 4 cols/band
  const int rem = lin - band * 396;
  const int rowBase = (rem >> 2) * 256;
  const int colBase = (band * 4 + (rem & 3)) * 256;

  // --- staging addresses (XOR-8 granule swizzle on the GLOBAL side, LDS linear)
  const int srow = lane >> 3;                       // row within 8-row group
  const int gk = ((lane & 7) ^ srow) * 8;           // swizzled k-offset (u16)
  const unsigned short* gA = A + (size_t)(rowBase + wv * 8 + srow) * 1024 + gk;
  const unsigned short* gB = Bt + (size_t)(colBase + wv * 8 + srow) * 1024 + gk;
  unsigned short* sAst = sA + wv * 512 + lane * 8;  // + i*4096 per 64-row group
  unsigned short* sBst = sB + wv * 512 + lane * 8;

  // --- fragment-read bases: slot = granule ^ (row&7) -> 2-way (free) bank pattern
  const int aOff = (wm * 128 + l15) * 64;
  const int bOff = (wn * 64 + l15) * 64;
  const int sl0 = ((kg) ^ (l15 & 7)) * 8;
  const int sl1 = ((4 + kg) ^ (l15 & 7)) * 8;

  f32x4 acc[8][4] = {};
  bf16x8 av0[8], av1[8], bv[4];

  // --- prologue: A(0),B(0) -> buf0 ; A(1) -> buf1 ; wait A0+B0 (A1 may fly)
#pragma unroll
  for (int i = 0; i < 4; i++) async16(gA + i * 65536, sAst + i * 4096);
#pragma unroll
  for (int i = 0; i < 4; i++) async16(gB + i * 65536, sBst + i * 4096);
#pragma unroll
  for (int i = 0; i < 4; i++) async16(gA + i * 65536 + 64, sAst + 16384 + i * 4096);
  asm volatile("s_waitcnt vmcnt(4)" ::: "memory");
  __builtin_amdgcn_s_barrier();
  asm volatile("" ::: "memory");

  // --- main loop: 16 K-tiles (K=1024, BK=64)
#pragma unroll 1
  for (int tp = 0; tp < 7; ++tp) {
    const int t0 = tp * 2;
    TILE_ONE(t0, 0, true, true, 4);
    TILE_ONE(t0 + 1, 1, true, true, 4);
  }
  TILE_ONE(14, 0, true, false, 0);
  TILE_ONE(15, 1, false, false, -1);

  // --- epilogue: stage C via LDS, coalesced 16B stores
  __syncthreads();
  if (MODE == 2) {
    float* Cf = (float*)lds;                        // [128][256] fp32, 2 passes
    float* outF = (float*)o.p[0];
#pragma unroll
    for (int p = 0; p < 2; ++p) {
      if (p) __syncthreads();
      if (wm == p) {
#pragma unroll
        for (int n = 0; n < 4; ++n) {
          const int col = wn * 64 + n * 16 + l15;
          const float bval = bias[colBase + col];
#pragma unroll
          for (int m = 0; m < 8; ++m)
#pragma unroll
            for (int r = 0; r < 4; ++r)
              Cf[(m * 16 + kg * 4 + r) * 256 + col] = acc[m][n][r] + bval;
        }
      }
      __syncthreads();
#pragma unroll
      for (int t2 = 0; t2 < 16; ++t2) {
        const int g = t2 * 512 + tid;
        const int row = g >> 6, ch = g & 63;
        const int grow = rowBase + p * 128 + row;
        if (grow < Mreal)
          *(float4*)(outF + (size_t)grow * 1024 + colBase + ch * 4) =
              *(const float4*)(Cf + row * 256 + ch * 4);
      }
    }
  } else {
    unsigned short* Cs = lds;                       // [256][256] u16, single pass
#pragma unroll
    for (int n = 0; n < 4; ++n) {
      const int col = wn * 64 + n * 16 + l15;
      const float bval = (MODE == 1) ? bias[colBase + col] : 0.f;
#pragma unroll
      for (int m = 0; m < 8; ++m)
#pragma unroll
        for (int r = 0; r < 4; ++r)
          Cs[(wm * 128 + m * 16 + kg * 4 + r) * 256 + col] = f2b(acc[m][n][r] + bval);
    }
    __syncthreads();
    unsigned short* C;
    int cbase;
    if (MODE == 3) { C = (unsigned short*)o.p[colBase >> 10]; cbase = colBase & 1023; }
    else { C = (unsigned short*)o.p[0]; cbase = colBase; }
#pragma unroll
    for (int t2 = 0; t2 < 16; ++t2) {
      const int g = t2 * 512 + tid;
      const int row = g >> 5, ch = g & 31;
      const int grow = rowBase + row;
      if (grow < Mreal)
        *(uint4*)(C + (size_t)grow * 1024 + cbase + ch * 8) =
            *(const uint4*)(Cs + row * 256 + ch * 8);
    }
  }
}

// ---------------- LayerNorm over rows of 1024, bf16 in/out ----------------
__global__ __launch_bounds__(256) void ln_kernel(const unsigned short* __restrict__ src,
                                                 const unsigned short* __restrict__ src0,
                                                 const float* __restrict__ g,
                                                 const float* __restrict__ beta,
                                                 unsigned short* __restrict__ out, int Mreal) {
  const int row = blockIdx.x, tid = threadIdx.x;
  unsigned short* op = out + (size_t)row * 1024 + tid * 4;
  if (row >= Mreal) {                       // zero the pad rows
    ushort4 z; z.x = 0; z.y = 0; z.z = 0; z.w = 0;
    *(ushort4*)op = z;
    return;
  }
  const unsigned short* s = src;
  if (src0 != nullptr && (row % L_T) == 0) s = src0;
  const unsigned short* ip = s + (size_t)row * 1024 + tid * 4;
  uint2 raw = *(const uint2*)ip;
  float x0 = b2f(raw.x & 0xffffu), x1 = b2f(raw.x >> 16);
  float x2 = b2f(raw.y & 0xffffu), x3 = b2f(raw.y >> 16);
  float sum = x0 + x1 + x2 + x3;
  float sq = x0 * x0 + x1 * x1 + x2 * x2 + x3 * x3;
#pragma unroll
  for (int off = 32; off > 0; off >>= 1) {
    sum += __shfl_down(sum, off);
    sq += __shfl_down(sq, off);
  }
  __shared__ float red[8];
  if ((tid & 63) == 0) { red[tid >> 6] = sum; red[4 + (tid >> 6)] = sq; }
  __syncthreads();
  const float ts = red[0] + red[1] + red[2] + red[3];
  const float tq = red[4] + red[5] + red[6] + red[7];
  const float mean = ts * (1.f / 1024.f);
  const float var = tq * (1.f / 1024.f) - mean * mean;
  const float rstd = rsqrtf(var + 1e-5f);
  const float4 gv = *(const float4*)(g + tid * 4);
  const float4 bv = *(const float4*)(beta + tid * 4);
  ushort4 o;
  o.x = f2b((x0 - mean) * rstd * gv.x + bv.x);
  o.y = f2b((x1 - mean) * rstd * gv.y + bv.y);
  o.z = f2b((x2 - mean) * rstd * gv.z + bv.z);
  o.w = f2b((x3 - mean) * rstd * gv.w + bv.w);
  *(ushort4*)op = o;
}

// ---------------- Attention ----------------
// type 1 (temporal, MFMA): 1 wave per s-problem (16 q x 17 k x 128d), 4 waves/block.
// type 0 (spatial, scalar fallback): block=(hb,f,qchunk), 16 q x 197 k.
// NOTE: jnp.tile(feat_k,(S,1,1)) means batch i uses feat head (i % 64), not its own head!
#define ATT_T_BLOCKS (64 * 49)    // 3136: hb x (196/4)
__global__ __launch_bounds__(256) void attn_kernel(const unsigned short* __restrict__ q,
                                                   const unsigned short* __restrict__ k,
                                                   const unsigned short* __restrict__ v,
                                                   unsigned short* __restrict__ out,
                                                   const int* __restrict__ att_type) {
  __shared__ __align__(16) char smem[22528];
  const int tid = threadIdx.x;
  const int bid = blockIdx.x;
  const int at = att_type[0];

  if (at == 1) {
    if (bid >= ATT_T_BLOCKS) return;
    const int lane = tid & 63, wv = tid >> 6;
    const int l15 = lane & 15, kg = lane >> 4;
    const int hb = bid / 49, sb = bid - hb * 49;
    const int s = sb * 4 + wv;                  // each wave owns one s
    const int n = hb >> 3, h = hb & 7;
    const int fi = (hb * S_T + s) & 63;         // tile() modular feat indexing
    const size_t frow = (size_t)(fi >> 3) * L_T;
    const int fcol = (fi & 7) * HD;
    const int qbase = n * L_T + 1 + s;
    const int hcol = h * HD;

    // wave-private LDS: P [16][32] bf16 (1KB) + V [17 keys][130 elem-stride] bf16
    unsigned short* Pl = (unsigned short*)(smem + wv * 5632);
    unsigned short* Vl = (unsigned short*)(smem + wv * 5632 + 1024);

    // ---- stage V rows coalesced into LDS (stride 130 -> conflict-free col reads)
    {
      const int dim0 = l15 * 8;
#pragma unroll
      for (int p = 0; p < 5; p++) {
        const int key = p * 4 + kg;
        if (key < 17) {
          const unsigned short* vp = (key == 0)
              ? (v + frow * 1024 + fcol + dim0)
              : (v + (size_t)(qbase + (key - 1) * S_T) * 1024 + hcol + dim0);
          uint4 r = *(const uint4*)vp;
          unsigned int* wp = (unsigned int*)Vl + key * 65 + l15 * 4;
          wp[0] = r.x; wp[1] = r.y; wp[2] = r.z; wp[3] = r.w;
        }
      }
    }

    // ---- Q fragments (A) and K fragments (B, natural layout) straight from global
    bf16x8 aq[4], bk0[4], bk1[4];
    {
      const unsigned short* qp = q + (size_t)(qbase + l15 * S_T) * 1024 + hcol + kg * 8;
      const unsigned short* kp = (l15 == 0)
          ? (k + frow * 1024 + fcol + kg * 8)                         // key 0 = feat
          : (k + (size_t)(qbase + (l15 - 1) * S_T) * 1024 + hcol + kg * 8);
      const unsigned short* kp1 = k + (size_t)(qbase + 15 * S_T) * 1024 + hcol + kg * 8;  // key 16
#pragma unroll
      for (int t = 0; t < 4; t++) {
        aq[t] = *(const bf16x8*)(qp + t * 32);
        bk0[t] = *(const bf16x8*)(kp + t * 32);
        if (l15 == 0) bk1[t] = *(const bf16x8*)(kp1 + t * 32);
        else {
          bf16x8 z = {};
          bk1[t] = z;
        }
      }
    }

    // ---- scores: c0 = keys 0..15, c1 col0 = key 16
    f32x4 c0 = {}, c1 = {};
#pragma unroll
    for (int t = 0; t < 4; t++) {
      c0 = __builtin_amdgcn_mfma_f32_16x16x32_bf16(aq[t], bk0[t], c0, 0, 0, 0);
      c1 = __builtin_amdgcn_mfma_f32_16x16x32_bf16(aq[t], bk1[t], c1, 0, 0, 0);
    }

    // ---- softmax in registers (16-lane butterflies), P -> LDS bf16
    const float scl = 0.08838834764831845f;   // 1/sqrt(128)
#pragma unroll
    for (int r = 0; r < 4; r++) {
      float v0 = c0[r] * scl;
      float k16 = __shfl(c1[r] * scl, lane & 48);   // col0 of this 16-lane group
      float mx = v0;
#pragma unroll
      for (int m = 1; m < 16; m <<= 1) mx = fmaxf(mx, __shfl_xor(mx, m));
      mx = fmaxf(mx, k16);
      float p = __expf(v0 - mx);
      float p16 = __expf(k16 - mx);
      float sum = p;
#pragma unroll
      for (int m = 1; m < 16; m <<= 1) sum += __shfl_xor(sum, m);
      sum += p16;
      const float inv = 1.f / sum;
      const int row = kg * 4 + r;                    // C layout: row=(lane>>4)*4+reg
      Pl[row * 32 + l15] = f2b(p * inv);
      Pl[row * 32 + 16 + l15] = (l15 == 0) ? f2b(p16 * inv) : (unsigned short)0;
    }

    // ---- PV: A = P (16x32, keys padded w/ 0), B = V^T gathered from LDS
    bf16x8 ap = *(const bf16x8*)(Pl + l15 * 32 + kg * 8);
#pragma unroll
    for (int nt = 0; nt < 8; nt++) {
      const int dim = nt * 16 + l15;
      bf16x8 bvv;
#pragma unroll
      for (int j = 0; j < 8; j++) {
        const int key = kg * 8 + j;
        const int kc = (key < 17) ? key : 0;
        unsigned short raw = Vl[kc * 130 + dim];
        bvv[j] = (key < 17) ? (short)raw : (short)0;
      }
      f32x4 z = {};
      f32x4 o = __builtin_amdgcn_mfma_f32_16x16x32_bf16(ap, bvv, z, 0, 0, 0);
#pragma unroll
      for (int r = 0; r < 4; r++) {
        const int qi = kg * 4 + r;
        out[(size_t)(qbase + qi * S_T) * 1024 + hcol + nt * 16 + l15] = f2b(o[r]);
      }
    }
    return;
  }

  // ---------------- spatial fallback (scalar; not exercised when att_type==1) ----------------
  float (*qs)[132] = (float (*)[132])smem;                    // 16*132*4 = 8448 B
  float (*sc)[212] = (float (*)[212])(smem + 8448);           // 16*212*4 = 13568 B
  const int hb = bid / 208;
  const int rem = bid - hb * 208;
  const int f = rem / 13, qc = rem - f * 13;
  const int n = hb >> 3, h = hb & 7;
  const int fi = (hb * F_T + f) & 63;
  const size_t frow = (size_t)(fi >> 3) * L_T;
  const int fcol = (fi & 7) * HD;
  const int kbase = n * L_T + 1 + f * S_T;
  const int qbase = kbase + qc * 16;
  const int nk = S_T + 1;
  const int nqv = (qc == 12) ? 4 : 16;
  const int hcol = h * HD;

  {
    const int i = tid >> 4, db = (tid & 15) * 8;
    float* dst = &qs[i][db];
    if (i < nqv) {
      const unsigned short* qp = q + (size_t)(qbase + i) * 1024 + hcol + db;
      uint4 r = *(const uint4*)qp;
      dst[0] = b2f(r.x & 0xffffu); dst[1] = b2f(r.x >> 16);
      dst[2] = b2f(r.y & 0xffffu); dst[3] = b2f(r.y >> 16);
      dst[4] = b2f(r.z & 0xffffu); dst[5] = b2f(r.z >> 16);
      dst[6] = b2f(r.w & 0xffffu); dst[7] = b2f(r.w >> 16);
    } else {
#pragma unroll
      for (int u = 0; u < 8; u++) dst[u] = 0.f;
    }
  }
  __syncthreads();

  const int nslot = 16 * nk;
  for (int slot = tid; slot < nslot; slot += 256) {
    const int i = slot / nk, j = slot - i * nk;
    const unsigned short* kp = (j == 0)
        ? (k + frow * 1024 + fcol)
        : (k + (size_t)(kbase + (j - 1)) * 1024 + hcol);
    float acc = 0.f;
#pragma unroll 4
    for (int d = 0; d < 128; d += 8) {
      uint4 r = *(const uint4*)(kp + d);
      acc += qs[i][d + 0] * b2f(r.x & 0xffffu);
      acc += qs[i][d + 1] * b2f(r.x >> 16);
      acc += qs[i][d + 2] * b2f(r.y & 0xffffu);
      acc += qs[i][d + 3] * b2f(r.y >> 16);
      acc += qs[i][d + 4] * b2f(r.z & 0xffffu);
      acc += qs[i][d + 5] * b2f(r.z >> 16);
      acc += qs[i][d + 6] * b2f(r.w & 0xffffu);
      acc += qs[i][d + 7] * b2f(r.w >> 16);
    }
    sc[i][j] = acc * 0.08838834764831845f;
  }
  __syncthreads();

  if (tid < 16) {
    const int i = tid;
    float m = -1e30f;
    for (int j = 0; j < nk; j++) m = fmaxf(m, sc[i][j]);
    float ssum = 0.f;
    for (int j = 0; j < nk; j++) {
      float e = __expf(sc[i][j] - m);
      sc[i][j] = e;
      ssum += e;
    }
    const float inv = 1.f / ssum;
    for (int j = 0; j < nk; j++) sc[i][j] *= inv;
  }
  __syncthreads();

  {
    const int i = tid >> 4, db = (tid & 15) * 8;
    float o[8];
#pragma unroll
    for (int u = 0; u < 8; u++) o[u] = 0.f;
    for (int j = 0; j < nk; j++) {
      const unsigned short* vp = (j == 0)
          ? (v + frow * 1024 + fcol + db)
          : (v + (size_t)(kbase + (j - 1)) * 1024 + hcol + db);
      const float p = sc[i][j];
      uint4 r = *(const uint4*)vp;
      o[0] += p * b2f(r.x & 0xffffu); o[1] += p * b2f(r.x >> 16);
      o[2] += p * b2f(r.y & 0xffffu); o[3] += p * b2f(r.y >> 16);
      o[4] += p * b2f(r.z & 0xffffu); o[5] += p * b2f(r.z >> 16);
      o[6] += p * b2f(r.w & 0xffffu); o[7] += p * b2f(r.w >> 16);
    }
    if (i < nqv) {
      unsigned short* op = out + (size_t)(qbase + i) * 1024 + hcol + db;
      uint4 w;
      w.x = (unsigned)f2b(o[0]) | ((unsigned)f2b(o[1]) << 16);
      w.y = (unsigned)f2b(o[2]) | ((unsigned)f2b(o[3]) << 16);
      w.z = (unsigned)f2b(o[4]) | ((unsigned)f2b(o[5]) << 16);
      w.w = (unsigned)f2b(o[6]) | ((unsigned)f2b(o[7]) << 16);
      *(uint4*)op = w;
    }
  }
}

// ---------------- host ----------------
extern "C" void kernel_launch(void* const* d_in, const int* in_sizes, int n_in,
                              void* d_out, int out_size, void* d_ws, size_t ws_size,
                              hipStream_t stream) {
  const float* x        = (const float*)d_in[0];
  const float* W_in     = (const float*)d_in[1];
  const float* b_in     = (const float*)d_in[2];
  const float* g_in     = (const float*)d_in[3];
  const float* beta_in  = (const float*)d_in[4];
  const float* W_q      = (const float*)d_in[5];
  const float* W_k      = (const float*)d_in[6];
  const float* W_v      = (const float*)d_in[7];
  const float* g_out    = (const float*)d_in[8];
  const float* beta_out = (const float*)d_in[9];
  const float* W_out    = (const float*)d_in[10];
  const float* b_out    = (const float*)d_in[11];
  const int* att_type   = (const int*)d_in[12];
  float* out = (float*)d_out;

  char* ws = (char*)d_ws;
  const size_t MB = (size_t)M_P * 1024 * 2;   // bf16 activation buffer
  unsigned short* xb = (unsigned short*)(ws + 0 * MB);  // x bf16 -> later attn out
  unsigned short* t1 = (unsigned short*)(ws + 1 * MB);  // gemm1 out -> later q
  unsigned short* xh = (unsigned short*)(ws + 2 * MB);  // ln1 out -> later ln2 out
  unsigned short* kb = (unsigned short*)(ws + 3 * MB);
  unsigned short* vb = (unsigned short*)(ws + 4 * MB);
  unsigned short* wt = (unsigned short*)(ws + 5 * MB);  // transposed bf16 weights
  const size_t WSZ = (size_t)1024 * 1024;
  unsigned short* wt_in  = wt;                // W_in^T
  unsigned short* wqkv   = wt + 1 * WSZ;      // [3072][1024]: Wq^T | Wk^T | Wv^T
  unsigned short* wt_out = wt + 4 * WSZ;      // W_out^T

  convert_pad<<<M_P, 256, 0, stream>>>(x, xb, M_R * 1024);

  WP wp;
  wp.s[0] = W_in; wp.s[1] = W_q; wp.s[2] = W_k; wp.s[3] = W_v; wp.s[4] = W_out;
  wp.d[0] = wt_in;
  wp.d[1] = wqkv;
  wp.d[2] = wqkv + 1 * WSZ;
  wp.d[3] = wqkv + 2 * WSZ;
  wp.d[4] = wt_out;
  transpose5<<<dim3(32, 32, 5), dim3(32, 8), 0, stream>>>(wp);

  Outs o1; o1.p[0] = t1; o1.p[1] = nullptr; o1.p[2] = nullptr;
  gemm_bt<1><<<396, 512, 0, stream>>>(xb, wt_in, b_in, o1, M_P);
  ln_kernel<<<M_P, 256, 0, stream>>>(t1, nullptr, g_in, beta_in, xh, M_R);

  Outs oq; oq.p[0] = t1; oq.p[1] = kb; oq.p[2] = vb;   // q -> t1
  gemm_bt<3><<<1188, 512, 0, stream>>>(xh, wqkv, nullptr, oq, M_P);

  attn_kernel<<<13312, 256, 0, stream>>>(t1, kb, vb, xb, att_type);
  ln_kernel<<<M_P, 256, 0, stream>>>(xb, t1, g_out, beta_out, xh, M_R);

  Outs oo; oo.p[0] = out; oo.p[1] = nullptr; oo.p[2] = nullptr;
  gemm_bt<2><<<396, 512, 0, stream>>>(xh, wt_out, b_out, oo, M_R);
}